// Round 6
// baseline (1003.232 us; speedup 1.0000x reference)
//
#include <hip/hip_runtime.h>
#include <math.h>
#include <float.h>

#define H 1080
#define W 1920
#define HWSZ (H*W)
#define NPART 25
#define NCH 26          // heatmap channels in memory (NPART+1)
#define NLIMB 26
#define KTOP 32
#define MID 10
#define RAD 12

#define EPS 1.2e-5f          // screen margin; hard two-sided f32 bound ~7e-6
#define BLCAP (1 << 20)      // global borderline-entry capacity (4 MB)

// vert_k geometry
#define VB 10                // LDS bounce batch rows
#define VCHUNK 50            // output rows per block (multiple of 25!)
// horiz_nms_k geometry
#define TH2 14
#define TW2 254
#define VTC 280              // vt cols (x0-13 .. x0+266)
#define VTS 281              // vt col stride (odd)
#define SMS 257              // smt col stride (256 cols real)

// Output layout (floats): px[25*32] py[25*32] score[25*32] mask[25*32] conn[26*32*32]
#define OFF_PY   800
#define OFF_SC   1600
#define OFF_MK   2400
#define OFF_CONN 3200

__device__ __constant__ int LIMBS_d[NLIMB * 2] = {
    1,8, 1,2, 1,5, 2,3, 3,4, 5,6, 6,7, 8,9, 9,10, 10,11, 8,12, 12,13, 13,14,
    1,0, 0,15, 15,16, 0,17, 0,18, 14,19, 19,20, 14,21, 11,22, 22,23, 11,24, 2,17, 5,18
};

__device__ __forceinline__ int symH(int y) {
    if (y < 0) return -1 - y;
    if (y >= H) return 2 * H - 1 - y;
    return y;
}
__device__ __forceinline__ int symW(int x) {
    if (x < 0) return -1 - x;
    if (x >= W) return 2 * W - 1 - x;
    return x;
}

// f32 weights, f64-derived (same op order as all prior rounds), SGPR-hoisted
__device__ __forceinline__ void make_w32(float* wr) {
    double wd[25]; double s = 0.0;
    #pragma unroll
    for (int t = 0; t < 25; ++t) {
        double u = (double)(t - 12) / 3.0;
        wd[t] = exp(-0.5 * u * u); s += wd[t];
    }
    #pragma unroll
    for (int t = 0; t < 25; ++t)
        wr[t] = __int_as_float(__builtin_amdgcn_readfirstlane(
                    __float_as_int((float)(wd[t] / s))));
}

// ---------------------------------------------------------------------------
// Pass 1: vertical blur, channels-last input read DIRECTLY (coalesced since
// consecutive threads = consecutive (x,c)). Rolling 25-tap register window,
// static circular indices (25-phase unroll). Planar write via LDS bounce.
// ---------------------------------------------------------------------------
__global__ __launch_bounds__(832) void vert_k(
    const float* __restrict__ hm, float* __restrict__ vpl)
{
    __shared__ float ld[VB][26][33];   // 34.3 KB
    const int tid = threadIdx.x;
    const int x0 = blockIdx.x * 32;
    const int ys = blockIdx.y * VCHUNK;
    const int c  = tid % 26;
    const int xo = tid / 26;           // 0..31
    const int gx = x0 + xo;

    float wr[25];
    make_w32(wr);

    const size_t cstr = (size_t)W * NCH;
    const size_t base = (size_t)gx * NCH + c;

    float win[25];
    #pragma unroll
    for (int k = 0; k < 24; ++k) {
        int ry = symH(ys - 12 + k);
        win[k] = hm[(size_t)ry * cstr + base];
    }
    win[24] = 0.f;

    #pragma unroll 1
    for (int blk = 0; blk < VCHUNK; blk += 25) {
        #pragma unroll
        for (int p = 0; p < 25; ++p) {
            const int yo = blk + p;
            const int y  = ys + yo;
            { int ry = symH(y + 12); win[(p + 24) % 25] = hm[(size_t)ry * cstr + base]; }
            float acc = 0.f;
            #pragma unroll
            for (int t = 0; t < 25; ++t)
                acc = fmaf(wr[t], win[(p + t) % 25], acc);   // t=0..24 order == prior rounds
            if (c < 25) ld[yo % VB][c][xo] = acc;
            if ((yo % VB) == VB - 1) {
                __syncthreads();
                const int c2 = tid >> 5, x2 = tid & 31;
                if (c2 < 25) {
                    const int yb = ys + yo - (VB - 1);
                    #pragma unroll
                    for (int i = 0; i < VB; ++i) {
                        int yr = yb + i;
                        if (yr < H)
                            vpl[(size_t)c2 * HWSZ + (size_t)yr * W + x0 + x2] = ld[i][c2][x2];
                    }
                }
                __syncthreads();
            }
        }
    }
}

// ---------------------------------------------------------------------------
// Pass 2: horizontal blur + NMS screen (identical f32 semantics to R5) +
// EPS borderline emission. sm overlays vt via union. Values gathered from hm.
// ---------------------------------------------------------------------------
__global__ __launch_bounds__(256) void horiz_nms_k(
    const float* __restrict__ vpl, const float* __restrict__ hm,
    float* __restrict__ cval, int* __restrict__ cidx,
    int* __restrict__ counters, unsigned int* __restrict__ blg, int cap)
{
    union U {
        float vt[16][VTS];    // 18.0 KB — consumed by horizontal pass
        float smt[16][SMS];   // 16.4 KB — overlaid after
    };
    __shared__ U u;
    __shared__ unsigned short cand[TH2 * TW2 + 28];  // 3584 entries, 7.2 KB
    __shared__ unsigned int bl[1024];                // 4 KB
    __shared__ int lcount, bcount, gbase, gbase2;

    const int tid = threadIdx.x;
    const int ch  = blockIdx.z;
    const int x0  = blockIdx.x * TW2;
    const int y0  = blockIdx.y * TH2;
    const float* vp = vpl + (size_t)ch * HWSZ;

    if (tid == 0) { lcount = 0; bcount = 0; }

    float wr[25];
    make_w32(wr);

    // load vt rows (coalesced planar reads; symmetric x-padding, y clamped —
    // OOB-row values are forced to 0 at smt store, matching z_row/z_col)
    for (int i = tid; i < 16 * VTC; i += 256) {
        int r = i / VTC, cc = i % VTC;
        int gy = y0 - 1 + r; gy = gy < 0 ? 0 : (gy >= H ? H - 1 : gy);
        int gx = symW(x0 - 13 + cc);
        u.vt[r][cc] = vp[(size_t)gy * W + gx];
    }
    __syncthreads();

    // horizontal: thread (r, g) -> sm cols g*16 .. g*16+15 of row r
    const int r = tid & 15, g = tid >> 4;
    float a[16];
    #pragma unroll
    for (int k = 0; k < 16; ++k) a[k] = 0.f;
    #pragma unroll
    for (int t = 0; t < 40; ++t) {
        float x = u.vt[r][g * 16 + t];
        #pragma unroll
        for (int k = 0; k < 16; ++k)
            if (t >= k && t < k + 25)
                a[k] = fmaf(wr[t - k], x, a[k]);   // per-output w index 0..24 ascending
    }
    __syncthreads();   // all vt reads done -> safe to overlay smt

    {
        const int gy_r = y0 - 1 + r;
        const bool rowok = (gy_r >= 0 && gy_r < H);
        #pragma unroll
        for (int k = 0; k < 16; ++k) {
            int j = g * 16 + k;
            int gxj = x0 - 1 + j;
            u.smt[r][j] = (rowok && gxj >= 0 && gxj < W) ? a[k] : 0.f;
        }
    }
    __syncthreads();

    // screen (R5 logic verbatim, new indexing)
    for (int i = tid; i < TH2 * TW2; i += 256) {
        int ly = i / TW2, lx = i % TW2;
        int gy = y0 + ly, gx = x0 + lx;
        if (gy >= H || gx >= W) continue;
        float s  = u.smt[ly + 1][lx + 1];
        float dT = s - 0.1f;
        float d0 = s - u.smt[ly][lx + 1];
        float d1 = s - u.smt[ly + 2][lx + 1];
        float d2 = s - u.smt[ly + 1][lx];
        float d3 = s - u.smt[ly + 1][lx + 2];
        int flags = (fabsf(dT) <= EPS ? 1 : 0)
                  | (fabsf(d0) <= EPS ? 2 : 0)
                  | (fabsf(d1) <= EPS ? 4 : 0)
                  | (fabsf(d2) <= EPS ? 8 : 0)
                  | (fabsf(d3) <= EPS ? 16 : 0);
        if (!flags) {
            if (dT > 0.f && d0 >= 0.f && d1 >= 0.f && d2 >= 0.f && d3 >= 0.f) {
                int pos = atomicAdd(&lcount, 1);
                cand[pos] = (unsigned short)((ly << 8) | lx);
            }
        } else {
            bool fail = (!(flags & 1)  && dT <= 0.f) ||
                        (!(flags & 2)  && d0 <  0.f) ||
                        (!(flags & 4)  && d1 <  0.f) ||
                        (!(flags & 8)  && d2 <  0.f) ||
                        (!(flags & 16) && d3 <  0.f);
            if (!fail) {
                unsigned int ent = ((unsigned int)ch << 26) | ((unsigned int)flags << 21)
                                 | (unsigned int)(gy * W + gx);
                int bp = atomicAdd(&bcount, 1);
                if (bp < 1024) bl[bp] = ent;
                else {
                    int gp = atomicAdd(&counters[32], 1);
                    if (gp < BLCAP) blg[gp] = ent;
                }
            }
        }
    }
    __syncthreads();

    // one global atomic per block per list, coalesced copy-out
    if (tid == 0) {
        gbase  = atomicAdd(&counters[ch], lcount);
        int nb = bcount < 1024 ? bcount : 1024;
        gbase2 = atomicAdd(&counters[32], nb);
    }
    __syncthreads();
    int n = lcount, b = gbase;
    for (int i = tid; i < n; i += 256) {
        int p = b + i;
        if (p < cap) {
            int e = cand[i];
            int ly = e >> 8, lx = e & 255;
            int gpix = (y0 + ly) * W + (x0 + lx);
            cval[(size_t)ch * cap + p] = hm[(size_t)gpix * NCH + ch];  // original bits
            cidx[(size_t)ch * cap + p] = gpix;
        }
    }
    int nb = bcount < 1024 ? bcount : 1024;
    for (int i = tid; i < nb; i += 256) {
        int gp = gbase2 + i;
        if (gp < BLCAP) blg[gp] = bl[i];
    }
}

// ---------------------------------------------------------------------------
// Kernel R: f64 recheck of borderline pixels (gathers from channels-last hm).
// ---------------------------------------------------------------------------
__device__ double sm64_eval(const float* __restrict__ hm, int ch,
                            const double* w64s, int y, int x)
{
    int lane = threadIdx.x & 63;
    double colsum = 0.0;
    if (lane < 25) {
        int cx = symW(x - RAD + lane);
        float xv[25];
        #pragma unroll
        for (int t = 0; t < 25; t++) {
            int ry = symH(y - RAD + t);
            xv[t] = hm[((size_t)ry * W + cx) * NCH + ch];
        }
        #pragma unroll
        for (int t = 0; t < 25; t++)
            colsum = fma(w64s[t], (double)xv[t], colsum);
    }
    double acc = 0.0;
    for (int ci = 0; ci < 25; ci++) {
        double cs = __shfl(colsum, ci, 64);
        acc = fma(w64s[ci], cs, acc);
    }
    return acc;
}

__global__ __launch_bounds__(64) void recheck_k(
    const float* __restrict__ hm,
    float* __restrict__ cval, int* __restrict__ cidx,
    int* __restrict__ counters, const unsigned int* __restrict__ blg, int cap)
{
    __shared__ double w64s[2 * RAD + 1];
    __shared__ double wsum;
    const int tid = threadIdx.x;
    if (tid < 2 * RAD + 1) {
        double t = (double)(tid - RAD) / 3.0;
        w64s[tid] = exp(-0.5 * t * t);
    }
    __syncthreads();
    if (tid == 0) {
        double s = 0.0;
        for (int i = 0; i < 2 * RAD + 1; i++) s += w64s[i];
        wsum = s;
    }
    __syncthreads();
    if (tid < 2 * RAD + 1) w64s[tid] /= wsum;
    __syncthreads();

    int total = counters[32];
    if (total > BLCAP) total = BLCAP;
    for (int e = blockIdx.x; e < total; e += gridDim.x) {
        unsigned int ent = blg[e];
        int ch    = (int)(ent >> 26);
        int flags = (int)((ent >> 21) & 31);
        int gpix  = (int)(ent & 0x1FFFFFu);
        int gy = gpix / W, gx = gpix - gy * W;
        double sc = sm64_eval(hm, ch, w64s, gy, gx);
        bool ok = (flags & 1) ? (sc > 0.1) : true;
        if (ok && (flags & 2))  { double nv = (gy - 1 >= 0) ? sm64_eval(hm, ch, w64s, gy - 1, gx) : 0.0; ok = (sc >= nv); }
        if (ok && (flags & 4))  { double nv = (gy + 1 <  H) ? sm64_eval(hm, ch, w64s, gy + 1, gx) : 0.0; ok = (sc >= nv); }
        if (ok && (flags & 8))  { double nv = (gx - 1 >= 0) ? sm64_eval(hm, ch, w64s, gy, gx - 1) : 0.0; ok = (sc >= nv); }
        if (ok && (flags & 16)) { double nv = (gx + 1 <  W) ? sm64_eval(hm, ch, w64s, gy, gx + 1) : 0.0; ok = (sc >= nv); }
        if (tid == 0 && ok) {
            int p = atomicAdd(&counters[ch], 1);
            if (p < cap) {
                cval[(size_t)ch * cap + p] = hm[(size_t)gpix * NCH + ch];
                cidx[(size_t)ch * cap + p] = gpix;
            }
        }
    }
}

// ---------------------------------------------------------------------------
// Fallback: exact-f64 gather version (used only if ws too small)
// ---------------------------------------------------------------------------
#define TH 32
#define TW 64
#define LR (TH + 2*RAD + 2)
#define LC 90
#define VRR 34
#define VC (TW + 2*RAD + 2)
#define SR 34
#define SC 66
__global__ __launch_bounds__(256) void blur_peaks_gather(
    const float* __restrict__ hm,
    float* __restrict__ cval, int* __restrict__ cidx,
    int* __restrict__ counters, int cap)
{
    __shared__ float  in_t[LR][LC];
    __shared__ double v[VRR][VC];
    __shared__ double smv[SR][SC];
    __shared__ double wgt[2 * RAD + 1];
    __shared__ double wsum;

    const int tid = threadIdx.x;
    const int ch  = blockIdx.x;
    const int x0  = blockIdx.y * TW;
    const int y0  = blockIdx.z * TH;

    if (tid < 2 * RAD + 1) {
        double t = (double)(tid - RAD) / 3.0;
        wgt[tid] = exp(-0.5 * t * t);
    }
    __syncthreads();
    if (tid == 0) {
        double s = 0.0;
        for (int i = 0; i < 2 * RAD + 1; i++) s += wgt[i];
        wsum = s;
    }
    __syncthreads();
    if (tid < 2 * RAD + 1) wgt[tid] /= wsum;

    for (int i = tid; i < LR * LC; i += 256) {
        int r = i / LC, c = i % LC;
        int gy = symH(y0 - RAD - 1 + r);
        int gx = symW(x0 - RAD - 1 + c);
        in_t[r][c] = hm[((size_t)gy * W + gx) * NCH + ch];
    }
    __syncthreads();

    for (int i = tid; i < VRR * VC; i += 256) {
        int r = i / VC, c = i % VC;
        double acc = 0.0;
        #pragma unroll
        for (int t = 0; t < 2 * RAD + 1; t++)
            acc = fma(wgt[t], (double)in_t[r + t][c], acc);
        v[r][c] = acc;
    }
    __syncthreads();

    for (int i = tid; i < SR * SC; i += 256) {
        int r = i / SC, cc = i % SC;
        int gy = y0 - 1 + r;
        int gx = x0 - 1 + cc;
        double acc = 0.0;
        if (gy >= 0 && gy < H && gx >= 0 && gx < W) {
            #pragma unroll
            for (int t = 0; t < 2 * RAD + 1; t++)
                acc = fma(wgt[t], v[r][cc + t], acc);
        }
        smv[r][cc] = acc;
    }
    __syncthreads();

    for (int i = tid; i < TH * TW; i += 256) {
        int ly = i / TW, lx = i % TW;
        int gy = y0 + ly, gx = x0 + lx;
        if (gy >= H || gx >= W) continue;
        double s = smv[ly + 1][lx + 1];
        if (s > 0.1 &&
            s >= smv[ly][lx + 1] && s >= smv[ly + 2][lx + 1] &&
            s >= smv[ly + 1][lx] && s >= smv[ly + 1][lx + 2]) {
            float val = in_t[ly + RAD + 1][lx + RAD + 1];
            int pos = atomicAdd(&counters[ch], 1);
            if (pos < cap) {
                cval[(size_t)ch * cap + pos] = val;
                cidx[(size_t)ch * cap + pos] = gy * W + gx;
            }
        }
    }
}

// ---------------------------------------------------------------------------
// Kernel B: per-channel exact top-32 by (value desc, index asc)
// ---------------------------------------------------------------------------
#define BT 128
__global__ __launch_bounds__(BT) void topk_kernel(
    const float* __restrict__ cval, const int* __restrict__ cidx,
    const int* __restrict__ counters, int cap, float* __restrict__ out)
{
    __shared__ unsigned long long lk[KTOP * BT];
    __shared__ unsigned long long rk[BT];
    __shared__ int rw[BT];
    __shared__ int winner;

    const int tid = threadIdx.x;
    const int ch  = blockIdx.x;
    int n = counters[ch];
    if (n > cap) n = cap;

    int cnt = 0;
    for (int j = tid; j < n; j += BT) {
        float v = cval[(size_t)ch * cap + j];
        unsigned int u = __float_as_uint(v);
        u = (u & 0x80000000u) ? ~u : (u | 0x80000000u);
        unsigned long long key =
            ((unsigned long long)u << 32) |
            (unsigned int)(0xFFFFFFFFu - (unsigned int)cidx[(size_t)ch * cap + j]);
        if (cnt == KTOP) {
            if (key <= lk[(KTOP - 1) * BT + tid]) continue;
            cnt = KTOP - 1;
        }
        int i = cnt;
        while (i > 0 && key > lk[(i - 1) * BT + tid]) {
            lk[i * BT + tid] = lk[(i - 1) * BT + tid];
            i--;
        }
        lk[i * BT + tid] = key;
        cnt++;
    }
    int cur = 0;
    __syncthreads();

    for (int k = 0; k < KTOP; k++) {
        rk[tid] = (cur < cnt) ? lk[cur * BT + tid] : 0ULL;
        rw[tid] = tid;
        __syncthreads();
        for (int s = BT / 2; s > 0; s >>= 1) {
            if (tid < s) {
                if (rk[tid + s] > rk[tid]) { rk[tid] = rk[tid + s]; rw[tid] = rw[tid + s]; }
            }
            __syncthreads();
        }
        if (tid == 0) {
            winner = rw[0];
            unsigned long long bk = rk[0];
            float px, py, sc, mk;
            if (bk == 0ULL) {
                int fake = k - n; if (fake < 0) fake = 0;
                px = (float)(fake % W); py = (float)(fake / W); sc = 0.f; mk = 0.f;
            } else {
                unsigned int u = (unsigned int)(bk >> 32);
                unsigned int fb = (u & 0x80000000u) ? (u ^ 0x80000000u) : ~u;
                float v = __uint_as_float(fb);
                int idx = (int)(0xFFFFFFFFu - (unsigned int)(bk & 0xFFFFFFFFu));
                px = (float)(idx % W); py = (float)(idx / W); sc = v; mk = 1.f;
            }
            out[ch * KTOP + k]          = px;
            out[OFF_PY + ch * KTOP + k] = py;
            out[OFF_SC + ch * KTOP + k] = sc;
            out[OFF_MK + ch * KTOP + k] = mk;
        }
        __syncthreads();
        if (tid == winner && cur < cnt) cur++;
        __syncthreads();
    }
}

// ---------------------------------------------------------------------------
// Kernel C: limb connection scores (26 x 32 x 32)
// ---------------------------------------------------------------------------
__global__ __launch_bounds__(1024) void limbs_kernel(
    const float* __restrict__ pk, const float* __restrict__ paf,
    float* __restrict__ out)
{
    const int l = blockIdx.x;
    const int tid = threadIdx.x;
    const int i = tid >> 5;
    const int j = tid & 31;
    const int A = LIMBS_d[2 * l], B = LIMBS_d[2 * l + 1];

    float ax = pk[A * KTOP + i],          ay = pk[OFF_PY + A * KTOP + i];
    float ma = pk[OFF_MK + A * KTOP + i];
    float bx = pk[B * KTOP + j],          by = pk[OFF_PY + B * KTOP + j];
    float mb = pk[OFF_MK + B * KTOP + j];

    float vx = bx - ax, vy = by - ay;
    float norm = sqrtf(vx * vx + vy * vy) + 1e-10f;
    float ux = vx / norm, uy = vy / norm;

    const float step = 1.0f / 9.0f;
    float sum = 0.f;
    #pragma unroll
    for (int m = 0; m < MID; m++) {
        float t = (float)m * step;
        int sx = (int)rintf(ax + vx * t);
        int sy = (int)rintf(ay + vy * t);
        const float* p = paf + ((size_t)sy * W + sx) * (2 * NLIMB) + 2 * l;
        sum += p[0] * ux + p[1] * uy;
    }
    float score = sum / (float)MID;
    score = score < 0.f ? 0.f : (score > 1.f ? 1.f : score);
    float res = (ma != 0.f && mb != 0.f) ? score : 0.f;
    out[OFF_CONN + l * (KTOP * KTOP) + i * KTOP + j] = res;
}

// ---------------------------------------------------------------------------
extern "C" void kernel_launch(void* const* d_in, const int* in_sizes, int n_in,
                              void* d_out, int out_size, void* d_ws, size_t ws_size,
                              hipStream_t stream)
{
    const float* hm  = (const float*)d_in[0];
    const float* paf = (const float*)d_in[1];
    float* out = (float*)d_out;

    const size_t vpl_bytes = (size_t)NPART * HWSZ * sizeof(float);  // ~207.4 MB
    const size_t bl_bytes  = (size_t)BLCAP * 4;                     // 4 MB
    const size_t head = 256;

    bool pathA = false;
    int cap = 1;
    if (ws_size > head + vpl_bytes + bl_bytes + (size_t)NPART * 8 * 4096 + 512) {
        size_t avail = ws_size - head - vpl_bytes - bl_bytes - 512;
        long long c = (long long)(avail / ((size_t)NPART * 8));
        cap = c > 65536 ? 65536 : (int)c;
        pathA = true;
    } else {
        size_t avail = ws_size > head ? ws_size - head : 0;
        long long c = (long long)(avail / ((size_t)NPART * 8));
        cap = c > 65536 ? 65536 : (int)c;
        if (cap < 1) cap = 1;
    }

    int*   counters = (int*)d_ws;
    float* cval = (float*)((char*)d_ws + head);
    int*   cidx = (int*)(cval + (size_t)NPART * cap);
    unsigned int* blg = (unsigned int*)(cidx + (size_t)NPART * cap);
    float* vpl = (float*)(blg + (pathA ? (size_t)BLCAP : 0));
    vpl = (float*)(((uintptr_t)vpl + 255) & ~(uintptr_t)255);

    hipMemsetAsync(d_ws, 0, head, stream);

    if (pathA) {
        dim3 g1(W / 32, (H + VCHUNK - 1) / VCHUNK);        // 60 x 22
        vert_k<<<g1, 832, 0, stream>>>(hm, vpl);
        dim3 g2((W + TW2 - 1) / TW2, (H + TH2 - 1) / TH2, NPART);  // 8 x 78 x 25
        horiz_nms_k<<<g2, 256, 0, stream>>>(vpl, hm, cval, cidx, counters, blg, cap);
        recheck_k<<<2048, 64, 0, stream>>>(hm, cval, cidx, counters, blg, cap);
    } else {
        dim3 gA(NPART, (W + TW - 1) / TW, (H + TH - 1) / TH);
        blur_peaks_gather<<<gA, 256, 0, stream>>>(hm, cval, cidx, counters, cap);
    }
    topk_kernel<<<NPART, BT, 0, stream>>>(cval, cidx, counters, cap, out);
    limbs_kernel<<<NLIMB, 1024, 0, stream>>>(out, paf, out);
}

// Round 7
// 732.968 us; speedup vs baseline: 1.3687x; 1.3687x over previous
//
#include <hip/hip_runtime.h>
#include <math.h>
#include <float.h>

#define H 1080
#define W 1920
#define HWSZ (H*W)
#define NPART 25
#define NCH 26          // heatmap channels in memory (NPART+1)
#define NLIMB 26
#define KTOP 32
#define MID 10
#define RAD 12

#define EPS 1.2e-5f          // screen margin; hard two-sided f32 bound ~7e-6
#define BLCAP (1 << 20)      // global borderline-entry capacity (4 MB)
#define NS 16                // top-k stage-1 slices per channel

// vert_k geometry
#define VB 10                // LDS bounce batch rows
#define VCHUNK 50            // output rows per block (multiple of 25!)
// horiz_nms_k geometry
#define TH2 14
#define TW2 254
#define VTC 280              // vt cols (x0-13 .. x0+266)
#define VTS 281              // vt col stride (odd)
#define SMS 257              // smt col stride (256 cols real)

// Output layout (floats): px[25*32] py[25*32] score[25*32] mask[25*32] conn[26*32*32]
#define OFF_PY   800
#define OFF_SC   1600
#define OFF_MK   2400
#define OFF_CONN 3200

__device__ __constant__ int LIMBS_d[NLIMB * 2] = {
    1,8, 1,2, 1,5, 2,3, 3,4, 5,6, 6,7, 8,9, 9,10, 10,11, 8,12, 12,13, 13,14,
    1,0, 0,15, 15,16, 0,17, 0,18, 14,19, 19,20, 14,21, 11,22, 22,23, 11,24, 2,17, 5,18
};

__device__ __forceinline__ int symH(int y) {
    if (y < 0) return -1 - y;
    if (y >= H) return 2 * H - 1 - y;
    return y;
}
__device__ __forceinline__ int symW(int x) {
    if (x < 0) return -1 - x;
    if (x >= W) return 2 * W - 1 - x;
    return x;
}

// f32 weights, f64-derived (same op order as all prior rounds), SGPR-hoisted
__device__ __forceinline__ void make_w32(float* wr) {
    double wd[25]; double s = 0.0;
    #pragma unroll
    for (int t = 0; t < 25; ++t) {
        double u = (double)(t - 12) / 3.0;
        wd[t] = exp(-0.5 * u * u); s += wd[t];
    }
    #pragma unroll
    for (int t = 0; t < 25; ++t)
        wr[t] = __int_as_float(__builtin_amdgcn_readfirstlane(
                    __float_as_int((float)(wd[t] / s))));
}

// ---------------------------------------------------------------------------
// Pass 1: vertical blur, channels-last input read DIRECTLY (coalesced since
// consecutive threads = consecutive (x,c)). Rolling 25-tap register window,
// static circular indices (25-phase unroll). Planar write via LDS bounce.
// ---------------------------------------------------------------------------
__global__ __launch_bounds__(832) void vert_k(
    const float* __restrict__ hm, float* __restrict__ vpl)
{
    __shared__ float ld[VB][26][33];   // 34.3 KB
    const int tid = threadIdx.x;
    const int x0 = blockIdx.x * 32;
    const int ys = blockIdx.y * VCHUNK;
    const int c  = tid % 26;
    const int xo = tid / 26;           // 0..31
    const int gx = x0 + xo;

    float wr[25];
    make_w32(wr);

    const size_t cstr = (size_t)W * NCH;
    const size_t base = (size_t)gx * NCH + c;

    float win[25];
    #pragma unroll
    for (int k = 0; k < 24; ++k) {
        int ry = symH(ys - 12 + k);
        win[k] = hm[(size_t)ry * cstr + base];
    }
    win[24] = 0.f;

    #pragma unroll 1
    for (int blk = 0; blk < VCHUNK; blk += 25) {
        #pragma unroll
        for (int p = 0; p < 25; ++p) {
            const int yo = blk + p;
            const int y  = ys + yo;
            { int ry = symH(y + 12); win[(p + 24) % 25] = hm[(size_t)ry * cstr + base]; }
            float acc = 0.f;
            #pragma unroll
            for (int t = 0; t < 25; ++t)
                acc = fmaf(wr[t], win[(p + t) % 25], acc);   // t=0..24 order == prior rounds
            if (c < 25) ld[yo % VB][c][xo] = acc;
            if ((yo % VB) == VB - 1) {
                __syncthreads();
                const int c2 = tid >> 5, x2 = tid & 31;
                if (c2 < 25) {
                    const int yb = ys + yo - (VB - 1);
                    #pragma unroll
                    for (int i = 0; i < VB; ++i) {
                        int yr = yb + i;
                        if (yr < H)
                            vpl[(size_t)c2 * HWSZ + (size_t)yr * W + x0 + x2] = ld[i][c2][x2];
                    }
                }
                __syncthreads();
            }
        }
    }
}

// ---------------------------------------------------------------------------
// Pass 2: horizontal blur + NMS screen (identical f32 semantics to R5) +
// EPS borderline emission. sm overlays vt via union. Values gathered from hm.
// ---------------------------------------------------------------------------
__global__ __launch_bounds__(256) void horiz_nms_k(
    const float* __restrict__ vpl, const float* __restrict__ hm,
    float* __restrict__ cval, int* __restrict__ cidx,
    int* __restrict__ counters, unsigned int* __restrict__ blg, int cap)
{
    union U {
        float vt[16][VTS];    // 18.0 KB — consumed by horizontal pass
        float smt[16][SMS];   // 16.4 KB — overlaid after
    };
    __shared__ U u;
    __shared__ unsigned short cand[TH2 * TW2 + 28];  // 3584 entries, 7.2 KB
    __shared__ unsigned int bl[1024];                // 4 KB
    __shared__ int lcount, bcount, gbase, gbase2;

    const int tid = threadIdx.x;
    const int ch  = blockIdx.z;
    const int x0  = blockIdx.x * TW2;
    const int y0  = blockIdx.y * TH2;
    const float* vp = vpl + (size_t)ch * HWSZ;

    if (tid == 0) { lcount = 0; bcount = 0; }

    float wr[25];
    make_w32(wr);

    // load vt rows (coalesced planar reads; symmetric x-padding, y clamped —
    // OOB-row values are forced to 0 at smt store, matching z_row/z_col)
    for (int i = tid; i < 16 * VTC; i += 256) {
        int r = i / VTC, cc = i % VTC;
        int gy = y0 - 1 + r; gy = gy < 0 ? 0 : (gy >= H ? H - 1 : gy);
        int gx = symW(x0 - 13 + cc);
        u.vt[r][cc] = vp[(size_t)gy * W + gx];
    }
    __syncthreads();

    // horizontal: thread (r, g) -> sm cols g*16 .. g*16+15 of row r
    const int r = tid & 15, g = tid >> 4;
    float a[16];
    #pragma unroll
    for (int k = 0; k < 16; ++k) a[k] = 0.f;
    #pragma unroll
    for (int t = 0; t < 40; ++t) {
        float x = u.vt[r][g * 16 + t];
        #pragma unroll
        for (int k = 0; k < 16; ++k)
            if (t >= k && t < k + 25)
                a[k] = fmaf(wr[t - k], x, a[k]);   // per-output w index 0..24 ascending
    }
    __syncthreads();   // all vt reads done -> safe to overlay smt

    {
        const int gy_r = y0 - 1 + r;
        const bool rowok = (gy_r >= 0 && gy_r < H);
        #pragma unroll
        for (int k = 0; k < 16; ++k) {
            int j = g * 16 + k;
            int gxj = x0 - 1 + j;
            u.smt[r][j] = (rowok && gxj >= 0 && gxj < W) ? a[k] : 0.f;
        }
    }
    __syncthreads();

    // screen (R5 logic verbatim, new indexing)
    for (int i = tid; i < TH2 * TW2; i += 256) {
        int ly = i / TW2, lx = i % TW2;
        int gy = y0 + ly, gx = x0 + lx;
        if (gy >= H || gx >= W) continue;
        float s  = u.smt[ly + 1][lx + 1];
        float dT = s - 0.1f;
        float d0 = s - u.smt[ly][lx + 1];
        float d1 = s - u.smt[ly + 2][lx + 1];
        float d2 = s - u.smt[ly + 1][lx];
        float d3 = s - u.smt[ly + 1][lx + 2];
        int flags = (fabsf(dT) <= EPS ? 1 : 0)
                  | (fabsf(d0) <= EPS ? 2 : 0)
                  | (fabsf(d1) <= EPS ? 4 : 0)
                  | (fabsf(d2) <= EPS ? 8 : 0)
                  | (fabsf(d3) <= EPS ? 16 : 0);
        if (!flags) {
            if (dT > 0.f && d0 >= 0.f && d1 >= 0.f && d2 >= 0.f && d3 >= 0.f) {
                int pos = atomicAdd(&lcount, 1);
                cand[pos] = (unsigned short)((ly << 8) | lx);
            }
        } else {
            bool fail = (!(flags & 1)  && dT <= 0.f) ||
                        (!(flags & 2)  && d0 <  0.f) ||
                        (!(flags & 4)  && d1 <  0.f) ||
                        (!(flags & 8)  && d2 <  0.f) ||
                        (!(flags & 16) && d3 <  0.f);
            if (!fail) {
                unsigned int ent = ((unsigned int)ch << 26) | ((unsigned int)flags << 21)
                                 | (unsigned int)(gy * W + gx);
                int bp = atomicAdd(&bcount, 1);
                if (bp < 1024) bl[bp] = ent;
                else {
                    int gp = atomicAdd(&counters[32], 1);
                    if (gp < BLCAP) blg[gp] = ent;
                }
            }
        }
    }
    __syncthreads();

    // one global atomic per block per list, coalesced copy-out
    if (tid == 0) {
        gbase  = atomicAdd(&counters[ch], lcount);
        int nb = bcount < 1024 ? bcount : 1024;
        gbase2 = atomicAdd(&counters[32], nb);
    }
    __syncthreads();
    int n = lcount, b = gbase;
    for (int i = tid; i < n; i += 256) {
        int p = b + i;
        if (p < cap) {
            int e = cand[i];
            int ly = e >> 8, lx = e & 255;
            int gpix = (y0 + ly) * W + (x0 + lx);
            cval[(size_t)ch * cap + p] = hm[(size_t)gpix * NCH + ch];  // original bits
            cidx[(size_t)ch * cap + p] = gpix;
        }
    }
    int nb = bcount < 1024 ? bcount : 1024;
    for (int i = tid; i < nb; i += 256) {
        int gp = gbase2 + i;
        if (gp < BLCAP) blg[gp] = bl[i];
    }
}

// ---------------------------------------------------------------------------
// Kernel R: f64 recheck of borderline pixels (gathers from channels-last hm).
// ---------------------------------------------------------------------------
__device__ double sm64_eval(const float* __restrict__ hm, int ch,
                            const double* w64s, int y, int x)
{
    int lane = threadIdx.x & 63;
    double colsum = 0.0;
    if (lane < 25) {
        int cx = symW(x - RAD + lane);
        float xv[25];
        #pragma unroll
        for (int t = 0; t < 25; t++) {
            int ry = symH(y - RAD + t);
            xv[t] = hm[((size_t)ry * W + cx) * NCH + ch];
        }
        #pragma unroll
        for (int t = 0; t < 25; t++)
            colsum = fma(w64s[t], (double)xv[t], colsum);
    }
    double acc = 0.0;
    for (int ci = 0; ci < 25; ci++) {
        double cs = __shfl(colsum, ci, 64);
        acc = fma(w64s[ci], cs, acc);
    }
    return acc;
}

__global__ __launch_bounds__(64) void recheck_k(
    const float* __restrict__ hm,
    float* __restrict__ cval, int* __restrict__ cidx,
    int* __restrict__ counters, const unsigned int* __restrict__ blg, int cap)
{
    __shared__ double w64s[2 * RAD + 1];
    __shared__ double wsum;
    const int tid = threadIdx.x;
    if (tid < 2 * RAD + 1) {
        double t = (double)(tid - RAD) / 3.0;
        w64s[tid] = exp(-0.5 * t * t);
    }
    __syncthreads();
    if (tid == 0) {
        double s = 0.0;
        for (int i = 0; i < 2 * RAD + 1; i++) s += w64s[i];
        wsum = s;
    }
    __syncthreads();
    if (tid < 2 * RAD + 1) w64s[tid] /= wsum;
    __syncthreads();

    int total = counters[32];
    if (total > BLCAP) total = BLCAP;
    for (int e = blockIdx.x; e < total; e += gridDim.x) {
        unsigned int ent = blg[e];
        int ch    = (int)(ent >> 26);
        int flags = (int)((ent >> 21) & 31);
        int gpix  = (int)(ent & 0x1FFFFFu);
        int gy = gpix / W, gx = gpix - gy * W;
        double sc = sm64_eval(hm, ch, w64s, gy, gx);
        bool ok = (flags & 1) ? (sc > 0.1) : true;
        if (ok && (flags & 2))  { double nv = (gy - 1 >= 0) ? sm64_eval(hm, ch, w64s, gy - 1, gx) : 0.0; ok = (sc >= nv); }
        if (ok && (flags & 4))  { double nv = (gy + 1 <  H) ? sm64_eval(hm, ch, w64s, gy + 1, gx) : 0.0; ok = (sc >= nv); }
        if (ok && (flags & 8))  { double nv = (gx - 1 >= 0) ? sm64_eval(hm, ch, w64s, gy, gx - 1) : 0.0; ok = (sc >= nv); }
        if (ok && (flags & 16)) { double nv = (gx + 1 <  W) ? sm64_eval(hm, ch, w64s, gy, gx + 1) : 0.0; ok = (sc >= nv); }
        if (tid == 0 && ok) {
            int p = atomicAdd(&counters[ch], 1);
            if (p < cap) {
                cval[(size_t)ch * cap + p] = hm[(size_t)gpix * NCH + ch];
                cidx[(size_t)ch * cap + p] = gpix;
            }
        }
    }
}

// ---------------------------------------------------------------------------
// Fallback: exact-f64 gather version (used only if ws too small)
// ---------------------------------------------------------------------------
#define TH 32
#define TW 64
#define LR (TH + 2*RAD + 2)
#define LC 90
#define VRR 34
#define VC (TW + 2*RAD + 2)
#define SR 34
#define SC 66
__global__ __launch_bounds__(256) void blur_peaks_gather(
    const float* __restrict__ hm,
    float* __restrict__ cval, int* __restrict__ cidx,
    int* __restrict__ counters, int cap)
{
    __shared__ float  in_t[LR][LC];
    __shared__ double v[VRR][VC];
    __shared__ double smv[SR][SC];
    __shared__ double wgt[2 * RAD + 1];
    __shared__ double wsum;

    const int tid = threadIdx.x;
    const int ch  = blockIdx.x;
    const int x0  = blockIdx.y * TW;
    const int y0  = blockIdx.z * TH;

    if (tid < 2 * RAD + 1) {
        double t = (double)(tid - RAD) / 3.0;
        wgt[tid] = exp(-0.5 * t * t);
    }
    __syncthreads();
    if (tid == 0) {
        double s = 0.0;
        for (int i = 0; i < 2 * RAD + 1; i++) s += wgt[i];
        wsum = s;
    }
    __syncthreads();
    if (tid < 2 * RAD + 1) wgt[tid] /= wsum;

    for (int i = tid; i < LR * LC; i += 256) {
        int r = i / LC, c = i % LC;
        int gy = symH(y0 - RAD - 1 + r);
        int gx = symW(x0 - RAD - 1 + c);
        in_t[r][c] = hm[((size_t)gy * W + gx) * NCH + ch];
    }
    __syncthreads();

    for (int i = tid; i < VRR * VC; i += 256) {
        int r = i / VC, c = i % VC;
        double acc = 0.0;
        #pragma unroll
        for (int t = 0; t < 2 * RAD + 1; t++)
            acc = fma(wgt[t], (double)in_t[r + t][c], acc);
        v[r][c] = acc;
    }
    __syncthreads();

    for (int i = tid; i < SR * SC; i += 256) {
        int r = i / SC, cc = i % SC;
        int gy = y0 - 1 + r;
        int gx = x0 - 1 + cc;
        double acc = 0.0;
        if (gy >= 0 && gy < H && gx >= 0 && gx < W) {
            #pragma unroll
            for (int t = 0; t < 2 * RAD + 1; t++)
                acc = fma(wgt[t], v[r][cc + t], acc);
        }
        smv[r][cc] = acc;
    }
    __syncthreads();

    for (int i = tid; i < TH * TW; i += 256) {
        int ly = i / TW, lx = i % TW;
        int gy = y0 + ly, gx = x0 + lx;
        if (gy >= H || gx >= W) continue;
        double s = smv[ly + 1][lx + 1];
        if (s > 0.1 &&
            s >= smv[ly][lx + 1] && s >= smv[ly + 2][lx + 1] &&
            s >= smv[ly + 1][lx] && s >= smv[ly + 1][lx + 2]) {
            float val = in_t[ly + RAD + 1][lx + RAD + 1];
            int pos = atomicAdd(&counters[ch], 1);
            if (pos < cap) {
                cval[(size_t)ch * cap + pos] = val;
                cidx[(size_t)ch * cap + pos] = gy * W + gx;
            }
        }
    }
}

// ---------------------------------------------------------------------------
// Kernel B1: per-(channel, slice) exact top-32 -> packed keys to s1.
// 16-way interleaved slices keep reads coalesced; 400 blocks fill the chip.
// ---------------------------------------------------------------------------
#define BT 128
__global__ __launch_bounds__(BT) void topk1_kernel(
    const float* __restrict__ cval, const int* __restrict__ cidx,
    const int* __restrict__ counters, int cap,
    unsigned long long* __restrict__ s1)
{
    __shared__ unsigned long long lk[KTOP * BT];
    __shared__ unsigned long long rk[BT];
    __shared__ int rw[BT];
    __shared__ int winner;

    const int tid = threadIdx.x;
    const int sl  = blockIdx.x;   // slice
    const int ch  = blockIdx.y;
    int n = counters[ch];
    if (n > cap) n = cap;

    int cnt = 0;
    for (int j = sl * BT + tid; j < n; j += NS * BT) {
        float v = cval[(size_t)ch * cap + j];
        unsigned int u = __float_as_uint(v);
        u = (u & 0x80000000u) ? ~u : (u | 0x80000000u);   // monotonic key
        unsigned long long key =
            ((unsigned long long)u << 32) |
            (unsigned int)(0xFFFFFFFFu - (unsigned int)cidx[(size_t)ch * cap + j]);
        if (cnt == KTOP) {
            if (key <= lk[(KTOP - 1) * BT + tid]) continue;
            cnt = KTOP - 1;
        }
        int i = cnt;
        while (i > 0 && key > lk[(i - 1) * BT + tid]) {
            lk[i * BT + tid] = lk[(i - 1) * BT + tid];
            i--;
        }
        lk[i * BT + tid] = key;
        cnt++;
    }
    int cur = 0;
    __syncthreads();

    for (int k = 0; k < KTOP; k++) {
        rk[tid] = (cur < cnt) ? lk[cur * BT + tid] : 0ULL;
        rw[tid] = tid;
        __syncthreads();
        for (int s = BT / 2; s > 0; s >>= 1) {
            if (tid < s) {
                if (rk[tid + s] > rk[tid]) { rk[tid] = rk[tid + s]; rw[tid] = rw[tid + s]; }
            }
            __syncthreads();
        }
        if (tid == 0) {
            winner = rw[0];
            s1[((size_t)ch * NS + sl) * KTOP + k] = rk[0];   // 0 = empty pad
        }
        __syncthreads();
        if (tid == winner && cur < cnt) cur++;
        __syncthreads();
    }
}

// ---------------------------------------------------------------------------
// Kernel B2: per-channel merge of NS*32=512 keys via LDS bitonic sort (desc),
// then rank-k decode with the lax.top_k filler semantics.
// ---------------------------------------------------------------------------
__global__ __launch_bounds__(BT) void topk2_kernel(
    const unsigned long long* __restrict__ s1,
    const int* __restrict__ counters, int cap, float* __restrict__ out)
{
    __shared__ unsigned long long sk[NS * KTOP];   // 512 keys, 4 KB
    const int tid = threadIdx.x;
    const int ch  = blockIdx.x;

    for (int i = tid; i < NS * KTOP; i += BT)
        sk[i] = s1[(size_t)ch * NS * KTOP + i];
    __syncthreads();

    // bitonic sort, descending
    for (int k = 2; k <= NS * KTOP; k <<= 1) {
        for (int j = k >> 1; j > 0; j >>= 1) {
            for (int t = tid; t < NS * KTOP; t += BT) {
                int ixj = t ^ j;
                if (ixj > t) {
                    unsigned long long a = sk[t], b = sk[ixj];
                    bool sw = ((t & k) == 0) ? (a < b) : (a > b);
                    if (sw) { sk[t] = b; sk[ixj] = a; }
                }
            }
            __syncthreads();
        }
    }

    int n = counters[ch];
    if (n > cap) n = cap;
    if (tid < KTOP) {
        unsigned long long bk = sk[tid];
        float px, py, sc, mk;
        if (bk == 0ULL) {
            int fake = tid - n; if (fake < 0) fake = 0;
            px = (float)(fake % W); py = (float)(fake / W); sc = 0.f; mk = 0.f;
        } else {
            unsigned int u = (unsigned int)(bk >> 32);
            unsigned int fb = (u & 0x80000000u) ? (u ^ 0x80000000u) : ~u;
            float v = __uint_as_float(fb);
            int idx = (int)(0xFFFFFFFFu - (unsigned int)(bk & 0xFFFFFFFFu));
            px = (float)(idx % W); py = (float)(idx / W); sc = v; mk = 1.f;
        }
        out[ch * KTOP + tid]          = px;
        out[OFF_PY + ch * KTOP + tid] = py;
        out[OFF_SC + ch * KTOP + tid] = sc;
        out[OFF_MK + ch * KTOP + tid] = mk;
    }
}

// ---------------------------------------------------------------------------
// Fallback single-stage top-k (ws-too-small path only)
// ---------------------------------------------------------------------------
__global__ __launch_bounds__(BT) void topk_kernel(
    const float* __restrict__ cval, const int* __restrict__ cidx,
    const int* __restrict__ counters, int cap, float* __restrict__ out)
{
    __shared__ unsigned long long lk[KTOP * BT];
    __shared__ unsigned long long rk[BT];
    __shared__ int rw[BT];
    __shared__ int winner;

    const int tid = threadIdx.x;
    const int ch  = blockIdx.x;
    int n = counters[ch];
    if (n > cap) n = cap;

    int cnt = 0;
    for (int j = tid; j < n; j += BT) {
        float v = cval[(size_t)ch * cap + j];
        unsigned int u = __float_as_uint(v);
        u = (u & 0x80000000u) ? ~u : (u | 0x80000000u);
        unsigned long long key =
            ((unsigned long long)u << 32) |
            (unsigned int)(0xFFFFFFFFu - (unsigned int)cidx[(size_t)ch * cap + j]);
        if (cnt == KTOP) {
            if (key <= lk[(KTOP - 1) * BT + tid]) continue;
            cnt = KTOP - 1;
        }
        int i = cnt;
        while (i > 0 && key > lk[(i - 1) * BT + tid]) {
            lk[i * BT + tid] = lk[(i - 1) * BT + tid];
            i--;
        }
        lk[i * BT + tid] = key;
        cnt++;
    }
    int cur = 0;
    __syncthreads();

    for (int k = 0; k < KTOP; k++) {
        rk[tid] = (cur < cnt) ? lk[cur * BT + tid] : 0ULL;
        rw[tid] = tid;
        __syncthreads();
        for (int s = BT / 2; s > 0; s >>= 1) {
            if (tid < s) {
                if (rk[tid + s] > rk[tid]) { rk[tid] = rk[tid + s]; rw[tid] = rw[tid + s]; }
            }
            __syncthreads();
        }
        if (tid == 0) {
            winner = rw[0];
            unsigned long long bk = rk[0];
            float px, py, sc, mk;
            if (bk == 0ULL) {
                int fake = k - n; if (fake < 0) fake = 0;
                px = (float)(fake % W); py = (float)(fake / W); sc = 0.f; mk = 0.f;
            } else {
                unsigned int u = (unsigned int)(bk >> 32);
                unsigned int fb = (u & 0x80000000u) ? (u ^ 0x80000000u) : ~u;
                float v = __uint_as_float(fb);
                int idx = (int)(0xFFFFFFFFu - (unsigned int)(bk & 0xFFFFFFFFu));
                px = (float)(idx % W); py = (float)(idx / W); sc = v; mk = 1.f;
            }
            out[ch * KTOP + k]          = px;
            out[OFF_PY + ch * KTOP + k] = py;
            out[OFF_SC + ch * KTOP + k] = sc;
            out[OFF_MK + ch * KTOP + k] = mk;
        }
        __syncthreads();
        if (tid == winner && cur < cnt) cur++;
        __syncthreads();
    }
}

// ---------------------------------------------------------------------------
// Kernel C: limb connection scores (26 x 32 x 32)
// ---------------------------------------------------------------------------
__global__ __launch_bounds__(1024) void limbs_kernel(
    const float* __restrict__ pk, const float* __restrict__ paf,
    float* __restrict__ out)
{
    const int l = blockIdx.x;
    const int tid = threadIdx.x;
    const int i = tid >> 5;
    const int j = tid & 31;
    const int A = LIMBS_d[2 * l], B = LIMBS_d[2 * l + 1];

    float ax = pk[A * KTOP + i],          ay = pk[OFF_PY + A * KTOP + i];
    float ma = pk[OFF_MK + A * KTOP + i];
    float bx = pk[B * KTOP + j],          by = pk[OFF_PY + B * KTOP + j];
    float mb = pk[OFF_MK + B * KTOP + j];

    float vx = bx - ax, vy = by - ay;
    float norm = sqrtf(vx * vx + vy * vy) + 1e-10f;
    float ux = vx / norm, uy = vy / norm;

    const float step = 1.0f / 9.0f;
    float sum = 0.f;
    #pragma unroll
    for (int m = 0; m < MID; m++) {
        float t = (float)m * step;
        int sx = (int)rintf(ax + vx * t);
        int sy = (int)rintf(ay + vy * t);
        const float* p = paf + ((size_t)sy * W + sx) * (2 * NLIMB) + 2 * l;
        sum += p[0] * ux + p[1] * uy;
    }
    float score = sum / (float)MID;
    score = score < 0.f ? 0.f : (score > 1.f ? 1.f : score);
    float res = (ma != 0.f && mb != 0.f) ? score : 0.f;
    out[OFF_CONN + l * (KTOP * KTOP) + i * KTOP + j] = res;
}

// ---------------------------------------------------------------------------
extern "C" void kernel_launch(void* const* d_in, const int* in_sizes, int n_in,
                              void* d_out, int out_size, void* d_ws, size_t ws_size,
                              hipStream_t stream)
{
    const float* hm  = (const float*)d_in[0];
    const float* paf = (const float*)d_in[1];
    float* out = (float*)d_out;

    const size_t vpl_bytes = (size_t)NPART * HWSZ * sizeof(float);  // ~207.4 MB
    const size_t bl_bytes  = (size_t)BLCAP * 4;                     // 4 MB
    const size_t s1_bytes  = (size_t)NPART * NS * KTOP * 8;         // 100 KB
    const size_t head = 256;

    bool pathA = false;
    int cap = 1;
    if (ws_size > head + vpl_bytes + bl_bytes + s1_bytes + (size_t)NPART * 8 * 4096 + 1024) {
        size_t avail = ws_size - head - vpl_bytes - bl_bytes - s1_bytes - 1024;
        long long c = (long long)(avail / ((size_t)NPART * 8));
        cap = c > 65536 ? 65536 : (int)c;
        pathA = true;
    } else {
        size_t avail = ws_size > head ? ws_size - head : 0;
        long long c = (long long)(avail / ((size_t)NPART * 8));
        cap = c > 65536 ? 65536 : (int)c;
        if (cap < 1) cap = 1;
    }

    int*   counters = (int*)d_ws;
    float* cval = (float*)((char*)d_ws + head);
    int*   cidx = (int*)(cval + (size_t)NPART * cap);
    unsigned int* blg = (unsigned int*)(cidx + (size_t)NPART * cap);
    unsigned long long* s1 = (unsigned long long*)(blg + (pathA ? (size_t)BLCAP : 0));
    float* vpl = (float*)(s1 + (pathA ? (size_t)NPART * NS * KTOP : 0));
    vpl = (float*)(((uintptr_t)vpl + 255) & ~(uintptr_t)255);

    hipMemsetAsync(d_ws, 0, head, stream);

    if (pathA) {
        dim3 g1(W / 32, (H + VCHUNK - 1) / VCHUNK);        // 60 x 22
        vert_k<<<g1, 832, 0, stream>>>(hm, vpl);
        dim3 g2((W + TW2 - 1) / TW2, (H + TH2 - 1) / TH2, NPART);  // 8 x 78 x 25
        horiz_nms_k<<<g2, 256, 0, stream>>>(vpl, hm, cval, cidx, counters, blg, cap);
        recheck_k<<<2048, 64, 0, stream>>>(hm, cval, cidx, counters, blg, cap);
        dim3 gt(NS, NPART);
        topk1_kernel<<<gt, BT, 0, stream>>>(cval, cidx, counters, cap, s1);
        topk2_kernel<<<NPART, BT, 0, stream>>>(s1, counters, cap, out);
    } else {
        dim3 gA(NPART, (W + TW - 1) / TW, (H + TH - 1) / TH);
        blur_peaks_gather<<<gA, 256, 0, stream>>>(hm, cval, cidx, counters, cap);
        topk_kernel<<<NPART, BT, 0, stream>>>(cval, cidx, counters, cap, out);
    }
    limbs_kernel<<<NLIMB, 1024, 0, stream>>>(out, paf, out);
}